// Round 13
// baseline (280.106 us; speedup 1.0000x reference)
//
#include <hip/hip_runtime.h>
#include <math.h>

#define NB   8
#define SS   1024
#define DD   512
#define HH   8
#define DKK  64
#define NEGF (-3.0e38f)
// score scale folded with log2(e): exp(x) == exp2(x*log2e)
#define SC   (0.125f * 1.4426950408889634f)

// OCCUPANCY LEDGER (R0-R12): residency driver is reported VGPR_Count.
// <=32 -> 2 blk/CU; 36-40 -> 1 blk/CU (~1.25x cost). LDS up to 68.6KB has
// NO residency effect at low VGPR (R10). attn FROZEN at R10 body (~158us).
// GEMM-internal structure is NOT on the total's critical path (R11 BK=64
// null; R12 2-phase null). R13 attacks per-kernel fixed cost: cvt_fp16
// DELETED — conversion folded into GEMM staging (reg-stage fp32->half8->
// ds_write; rounding identical to cvt's cast -> bit-identical output).
#define QSTR 88             // halves; q tile stride
#define SCHUNK (16 * 256)   // floats per score chunk buffer (XOR swizzled)
#define PSTR 280            // halves; attn p rows (phase 3, aliased)

typedef _Float16 half8 __attribute__((ext_vector_type(8)));
typedef float    f32x4 __attribute__((ext_vector_type(4)));

// async 16B/lane global->LDS (wave-uniform LDS base + lane*16)
#define GLDS16(g, l) __builtin_amdgcn_global_load_lds( \
    (const __attribute__((address_space(1))) void*)(g), \
    (__attribute__((address_space(3))) void*)(l), 16, 0, 0)

// load 8 fp32, convert to 8 fp16 (same rounding as the old cvt kernel)
__device__ __forceinline__ half8 cvt8(const float* __restrict__ s) {
    float4 f0 = *(const float4*)s;
    float4 f1 = *(const float4*)(s + 4);
    return (half8){(_Float16)f0.x, (_Float16)f0.y, (_Float16)f0.z, (_Float16)f0.w,
                   (_Float16)f1.x, (_Float16)f1.y, (_Float16)f1.z, (_Float16)f1.w};
}

// ---------------------------------------------------------------------------
// DPP helpers: full-rate VALU cross-lane (no ds_bpermute).
// ---------------------------------------------------------------------------
template<int CTRL, int RM, int BM, bool BC>
__device__ __forceinline__ float dpp_f(float x) {
    return __builtin_bit_cast(float,
        __builtin_amdgcn_update_dpp(0, __builtin_bit_cast(int, x),
                                    CTRL, RM, BM, BC));
}

// inclusive 64-lane prefix sum: row_shr 1/2/4/8 then row_bcast:15 (rows 1,3)
// and row_bcast:31 (rows 2,3). old=0 so masked/invalid lanes add 0.
__device__ __forceinline__ float scan64(float x) {
    x += dpp_f<0x111, 0xf, 0xf, true >(x);   // row_shr:1
    x += dpp_f<0x112, 0xf, 0xf, true >(x);   // row_shr:2
    x += dpp_f<0x114, 0xf, 0xf, true >(x);   // row_shr:4
    x += dpp_f<0x118, 0xf, 0xf, true >(x);   // row_shr:8
    x += dpp_f<0x142, 0xa, 0xf, false>(x);   // row_bcast:15 -> rows 1,3
    x += dpp_f<0x143, 0xc, 0xf, false>(x);   // row_bcast:31 -> rows 2,3
    return x;
}

__device__ __forceinline__ float redsum64(float x) {
    x += dpp_f<0xB1,  0xf, 0xf, true>(x);    // quad_perm [1,0,3,2]  (xor 1)
    x += dpp_f<0x4E,  0xf, 0xf, true>(x);    // quad_perm [2,3,0,1]  (xor 2)
    x += dpp_f<0x141, 0xf, 0xf, true>(x);    // row_half_mirror      (xor 4)
    x += dpp_f<0x140, 0xf, 0xf, true>(x);    // row_mirror           (xor 8)
    x += __shfl_xor(x, 16);
    x += __shfl_xor(x, 32);
    return x;
}

__device__ __forceinline__ float bcast63(float x) {
    return __builtin_bit_cast(float,
        __builtin_amdgcn_readlane(__builtin_bit_cast(int, x), 63));
}

// ---------------------------------------------------------------------------
// GEMM #1 — R13: cvt fused. A (x) and B (Wk/Wv) are fp32 in HBM; staging
// reg-converts to fp16 LDS tiles (2-phase double buffer, one barrier/step).
// BK=64, 128x128 tile. MFMA sequence identical to R12 -> same absmax.
// q = x@Wk^T + bk -> fp16 [b,h,s,dk]; v = x@Wv^T + bv -> fp16 [b,h,dk,s].
// ---------------------------------------------------------------------------
__global__ __launch_bounds__(256) void gemm_qv(
    const float* __restrict__ xf,
    const float* __restrict__ wk, const float* __restrict__ bk,
    const float* __restrict__ wv, const float* __restrict__ bv,
    _Float16* __restrict__ q_ws, _Float16* __restrict__ vt_ws)
{
    __shared__ __align__(16) _Float16 Ah[2][128 * 64];   // 2 x 16 KB
    __shared__ __align__(16) _Float16 Bh[2][128 * 64];

    const int m0  = blockIdx.x * 128;
    const int n0c = blockIdx.y * 128;
    const bool is_v = (n0c >= DD);
    const float* __restrict__ Wp = is_v ? wv : wk;
    const float* __restrict__ bp = is_v ? bv : bk;
    const int n0 = n0c & (DD - 1);

    const int tid  = threadIdx.x;
    const int w    = tid >> 6;
    const int lane = tid & 63;
    const int quad = lane >> 4;
    const int n    = lane & 15;
    const int wm   = w >> 1, wn = w & 1;

    const int ci = (w * 4) * 64 + lane;   // c adds 64
    f32x4 acc[4][4] = {};

    // prologue: stage k0=0 into buffer 0 (reg-convert path)
    #pragma unroll
    for (int c = 0; c < 4; ++c) {
        const int cc = ci + c * 64;
        const int r  = cc >> 3, co = (cc & 7) * 8;
        *(half8*)&Ah[0][(w * 4 + c) * 512 + lane * 8] =
            cvt8(&xf[(size_t)(m0 + r) * DD + co]);
        *(half8*)&Bh[0][(w * 4 + c) * 512 + lane * 8] =
            cvt8(&Wp[(size_t)(n0 + r) * DD + co]);
    }
    __syncthreads();

    #pragma unroll
    for (int step = 0; step < 8; ++step) {
        const int cur = step & 1;
        const int nxt = cur ^ 1;
        const int k0  = step * 64;
        if (step < 7) {
            #pragma unroll
            for (int c = 0; c < 4; ++c) {
                const int cc = ci + c * 64;
                const int r  = cc >> 3, co = (cc & 7) * 8;
                *(half8*)&Ah[nxt][(w * 4 + c) * 512 + lane * 8] =
                    cvt8(&xf[(size_t)(m0 + r) * DD + k0 + 64 + co]);
                *(half8*)&Bh[nxt][(w * 4 + c) * 512 + lane * 8] =
                    cvt8(&Wp[(size_t)(n0 + r) * DD + k0 + 64 + co]);
            }
        }
        #pragma unroll
        for (int kf = 0; kf < 2; ++kf) {
            half8 af[4], bf[4];
            #pragma unroll
            for (int mi = 0; mi < 4; ++mi)
                af[mi] = *(const half8*)&Ah[cur][(wm*64 + mi*16 + n) * 64 + kf*32 + quad*8];
            #pragma unroll
            for (int ni = 0; ni < 4; ++ni)
                bf[ni] = *(const half8*)&Bh[cur][(wn*64 + ni*16 + n) * 64 + kf*32 + quad*8];
            #pragma unroll
            for (int mi = 0; mi < 4; ++mi)
                #pragma unroll
                for (int ni = 0; ni < 4; ++ni)
                    acc[mi][ni] = __builtin_amdgcn_mfma_f32_16x16x32_f16(
                        af[mi], bf[ni], acc[mi][ni], 0, 0, 0);
        }
        __syncthreads();
    }

    #pragma unroll
    for (int mi = 0; mi < 4; ++mi) {
        #pragma unroll
        for (int ni = 0; ni < 4; ++ni) {
            const int col = n0 + wn*64 + ni*16 + n;   // 0..511
            const int h   = col >> 6;
            const int dk  = col & 63;
            const float bias = bp[col];
            const int gbase = m0 + wm*64 + mi*16 + quad*4;
            const int bidx  = gbase >> 10;
            const int sr    = gbase & (SS - 1);
            if (!is_v) {
                #pragma unroll
                for (int reg = 0; reg < 4; ++reg)
                    q_ws[((size_t)(bidx * HH + h) * SS + sr + reg) * DKK + dk] =
                        (_Float16)(acc[mi][ni][reg] + bias);
            } else {
                _Float16 h4[4];
                #pragma unroll
                for (int reg = 0; reg < 4; ++reg)
                    h4[reg] = (_Float16)(acc[mi][ni][reg] + bias);
                *(uint2*)&vt_ws[((size_t)(bidx * HH + h) * DKK + dk) * SS + sr] =
                    *(uint2*)h4;
            }
        }
    }
}

// ---------------------------------------------------------------------------
// GEMM #2 — R13: A = attn_h (fp16, GLDS16 DMA path); B = Wo fp32,
// reg-converted in staging. out = attn_h @ Wo^T + bo.
// ---------------------------------------------------------------------------
__global__ __launch_bounds__(256) void gemm_out(
    const _Float16* __restrict__ A,
    const float* __restrict__ wo, const float* __restrict__ bo,
    float* __restrict__ out)
{
    __shared__ __align__(16) _Float16 Ah[2][128 * 64];
    __shared__ __align__(16) _Float16 Bh[2][128 * 64];

    const int m0 = blockIdx.x * 128;
    const int n0 = blockIdx.y * 128;

    const int tid  = threadIdx.x;
    const int w    = tid >> 6;
    const int lane = tid & 63;
    const int quad = lane >> 4;
    const int n    = lane & 15;
    const int wm   = w >> 1, wn = w & 1;

    const int ci = (w * 4) * 64 + lane;
    f32x4 acc[4][4] = {};

    #pragma unroll
    for (int c = 0; c < 4; ++c) {
        const int cc = ci + c * 64;
        const int r  = cc >> 3, co = (cc & 7) * 8;
        GLDS16(&A[(size_t)(m0 + r) * DD + co], &Ah[0][(w * 4 + c) * 512]);
        *(half8*)&Bh[0][(w * 4 + c) * 512 + lane * 8] =
            cvt8(&wo[(size_t)(n0 + r) * DD + co]);
    }
    __syncthreads();

    #pragma unroll
    for (int step = 0; step < 8; ++step) {
        const int cur = step & 1;
        const int nxt = cur ^ 1;
        const int k0  = step * 64;
        if (step < 7) {
            #pragma unroll
            for (int c = 0; c < 4; ++c) {
                const int cc = ci + c * 64;
                const int r  = cc >> 3, co = (cc & 7) * 8;
                GLDS16(&A[(size_t)(m0 + r) * DD + k0 + 64 + co],
                       &Ah[nxt][(w * 4 + c) * 512]);
                *(half8*)&Bh[nxt][(w * 4 + c) * 512 + lane * 8] =
                    cvt8(&wo[(size_t)(n0 + r) * DD + k0 + 64 + co]);
            }
        }
        #pragma unroll
        for (int kf = 0; kf < 2; ++kf) {
            half8 af[4], bf[4];
            #pragma unroll
            for (int mi = 0; mi < 4; ++mi)
                af[mi] = *(const half8*)&Ah[cur][(wm*64 + mi*16 + n) * 64 + kf*32 + quad*8];
            #pragma unroll
            for (int ni = 0; ni < 4; ++ni)
                bf[ni] = *(const half8*)&Bh[cur][(wn*64 + ni*16 + n) * 64 + kf*32 + quad*8];
            #pragma unroll
            for (int mi = 0; mi < 4; ++mi)
                #pragma unroll
                for (int ni = 0; ni < 4; ++ni)
                    acc[mi][ni] = __builtin_amdgcn_mfma_f32_16x16x32_f16(
                        af[mi], bf[ni], acc[mi][ni], 0, 0, 0);
        }
        __syncthreads();
    }

    #pragma unroll
    for (int mi = 0; mi < 4; ++mi) {
        #pragma unroll
        for (int ni = 0; ni < 4; ++ni) {
            const int col  = n0 + wn*64 + ni*16 + n;
            const float bias = bo[col];
            const int gbase = m0 + wm*64 + mi*16 + quad*4;
            #pragma unroll
            for (int reg = 0; reg < 4; ++reg)
                out[(size_t)(gbase + reg) * DD + col] = acc[mi][ni][reg] + bias;
        }
    }
}

// ---------------------------------------------------------------------------
// MFMA attention — R10 body, FROZEN (157.5us, VGPR 28, 2 blk/CU):
// single-barrier Phase 1 (#pragma unroll 1 dynamic loop, per-chunk buffers),
// swapped-operand QK^T, XOR swizzle, R9 Phase 2 (no cs[16]), flat PV.
// Known-toxic (do not retry): forced 2-blk/CU launch_bounds (R3, spill);
// reported VGPR > 32 (R5-R8); sched_barrier-pinned raw barriers + manual
// cross-barrier prefetch (R5, m141); 16-wave PV + o_red; utT fold + tmax;
// 8-wave blocks (old session).
// ---------------------------------------------------------------------------
__global__ __launch_bounds__(1024) void attn_mfma(
    const _Float16* __restrict__ q,   // [B,H,S,DK] fp16 (K = Q)
    const _Float16* __restrict__ vt,  // [B,H,DK,S] fp16 (V transposed)
    const float* __restrict__ utT,    // [B,S,S]
    const float* __restrict__ gammas, // [H]
    _Float16* __restrict__ attn)      // [B,S,H,DK] fp16
{
    // phase 1: 4 x SCHUNK f32 = 65536 B; phase 3 aliases 4x16xPSTR halves
    // (35840 B) inside it. + q_lds 2816 B = 68352 B total.
    __shared__ __align__(16) unsigned char smem[4 * SCHUNK * 4];
    __shared__ __align__(16) _Float16 q_lds[16 * QSTR];
    float*    s_lds = (float*)smem;
    _Float16* p_lds = (_Float16*)smem;

    const int tid  = threadIdx.x;
    const int w    = tid >> 6;
    const int lane = tid & 63;
    const int quad = lane >> 4;
    const int n    = lane & 15;
    const int bh   = blockIdx.y;
    const int b    = bh >> 3;
    const int h    = bh & 7;
    // heavy-first (LPT): largest r0 dispatched first, light blocks fill tail
    const int r0   = ((SS / 16 - 1) - blockIdx.x) * 16;

    const _Float16* __restrict__ kq  = q  + (size_t)bh * SS * DKK;
    const _Float16* __restrict__ vtp = vt + (size_t)bh * DKK * SS;

    const int nchunk = (r0 + 16 + 255) >> 8;   // 1..4, block-uniform
    const int nt     = nchunk * 4;
    const int i_lane = r0 + n;   // q-row owned by this lane in phase 1

    // stage Q tile into LDS (keeps qa fragments out of long-lived VGPRs)
    if (tid < 256) {
        const int row = tid >> 4;
        const int c   = tid & 15;
        *(uint2*)&q_lds[row * QSTR + c * 4] =
            *(const uint2*)&kq[(size_t)(r0 + row) * DKK + c * 4];
    }
    __syncthreads();

    const float* __restrict__ utrow = &utT[((size_t)b * SS + i_lane) * SS];
    const int scol = (w * 16 + quad * 4) ^ ((n & 7) << 2);   // store swizzle
    const int pcol = lane ^ ((w & 7) << 2);                  // pull swizzle

    // ---- Phase 1: dynamic loop, per-chunk buffers, NO inter-chunk barrier
    #pragma unroll 1
    for (int c0 = 0; c0 < nchunk; ++c0) {
        const int jbase = c0 * 256 + w * 16;
        f32x4 v;
        if (jbase <= r0 + 15) {        // wave-uniform guard
            half8 qa0 = *(const half8*)&q_lds[n * QSTR + quad * 8];
            half8 qa1 = *(const half8*)&q_lds[n * QSTR + 32 + quad * 8];
            const _Float16* krow = &kq[(size_t)(jbase + n) * DKK];
            half8 k0 = *(const half8*)&krow[quad * 8];
            half8 k1 = *(const half8*)&krow[32 + quad * 8];
            f32x4 ut = *(const f32x4*)&utrow[jbase + quad * 4];
            f32x4 d = {0.f, 0.f, 0.f, 0.f};
            d = __builtin_amdgcn_mfma_f32_16x16x32_f16(k0, qa0, d, 0, 0, 0);
            d = __builtin_amdgcn_mfma_f32_16x16x32_f16(k1, qa1, d, 0, 0, 0);
            #pragma unroll
            for (int reg = 0; reg < 4; ++reg) {
                const int j = jbase + quad * 4 + reg;
                v[reg] = (j <= i_lane) ? d[reg] * SC * ut[reg] : NEGF;
            }
        } else {
            v = (f32x4){NEGF, NEGF, NEGF, NEGF};
        }
        *(f32x4*)&s_lds[c0 * SCHUNK + n * 256 + scol] = v;
    }
    __syncthreads();   // ONE barrier for the whole phase

    float sreg[16];
    #pragma unroll
    for (int c0 = 0; c0 < 4; ++c0) {
        if (c0 < nchunk) {
            #pragma unroll
            for (int ttl = 0; ttl < 4; ++ttl)
                sreg[c0 * 4 + ttl] =
                    s_lds[c0 * SCHUNK + w * 256 + ttl * 64 + pcol];
        }
    }

    // ---- Phase 2 ----
    const int i_row = r0 + w;
    const int ntw_u = (i_row >> 6) + 1;          // tiles intersecting causal
    const int ntw   = (nt < ntw_u) ? nt : ntw_u; // wave-uniform

    // pass A: z1 = row total of e — plain sum per lane + one butterfly.
    float z1acc = 0.f;
    #pragma unroll
    for (int t2 = 0; t2 < 16; ++t2)
        if (t2 < ntw) z1acc += __builtin_amdgcn_exp2f(sreg[t2]);
    const float z1     = redsum64(z1acc);
    const float inv_z1 = 1.0f / z1;

    const float g     = gammas[h];
    const float gl2   = -log1pf(__expf(g)) * 1.4426950408889634f; // gamma*log2e
    const float flane = (float)lane;

    // pass B: inline scan (e recomputed bit-identically), decay, numerator
    float carry = 0.f;
    float z2 = 0.f;
    #pragma unroll
    for (int t2 = 0; t2 < 16; ++t2) {
        if (t2 < ntw) {
            const float e  = __builtin_amdgcn_exp2f(sreg[t2]); // masked -> 0
            const float xv = scan64(e);
            const float cs = carry + xv;
            carry += bcast63(xv);
            const float pe = (float)(i_row - t2 * 64) - flane;  // <0 only masked
            const float dd = fmaxf((z1 - cs) * pe, 0.0f) * inv_z1;
            float te = __builtin_amdgcn_exp2f(__builtin_amdgcn_sqrtf(dd) * gl2);
            te = fmaxf(te, 1e-5f);            // gamma<0 -> te<=1, no hi clamp
            const float p = __builtin_amdgcn_exp2f(sreg[t2] * te); // masked -> 0
            sreg[t2] = p;
            z2 += p;
        } else {
            sreg[t2] = 0.f;                   // tiles beyond causal extent
        }
    }
    z2 = redsum64(z2);
    const float inv_z2 = 1.0f / z2;

    __syncthreads();   // all phase-1 s_lds pulls complete before p writes

    // ---- Phase 3: flat PV, 2-deep prefetch ----
    #pragma unroll
    for (int c0 = 0; c0 < 4; ++c0) {
        if (c0 < nchunk) {
            #pragma unroll
            for (int ttl = 0; ttl < 4; ++ttl)
                p_lds[c0 * 16 * PSTR + w * PSTR + ttl * 64 + lane] =
                    (_Float16)(sreg[c0 * 4 + ttl] * inv_z2);
        }
    }

    const int KT = (r0 + 16 + 31) >> 5;   // 1..32 k-tiles of 32 cols, uniform
    const _Float16* vrow = &vtp[(size_t)(w * 16 + n) * SS];
    half8 vb[2] = {};
    if (w < 4) {
        #pragma unroll
        for (int u = 0; u < 2; ++u)
            if (u < KT) vb[u] = *(const half8*)&vrow[u * 32 + quad * 8];
    }
    __syncthreads();

    f32x4 oacc = {0.f, 0.f, 0.f, 0.f};
    if (w < 4) {
        for (int kt0 = 0; kt0 < KT; kt0 += 2) {
            half8 cur0 = vb[0], cur1 = vb[1];
            if (kt0 + 2 < KT) vb[0] = *(const half8*)&vrow[(kt0 + 2) * 32 + quad * 8];
            if (kt0 + 3 < KT) vb[1] = *(const half8*)&vrow[(kt0 + 3) * 32 + quad * 8];
            {
                half8 a = *(const half8*)&p_lds[((kt0 >> 3) * 16 + n) * PSTR +
                                                (kt0 & 7) * 32 + quad * 8];
                oacc = __builtin_amdgcn_mfma_f32_16x16x32_f16(a, cur0, oacc, 0, 0, 0);
            }
            if (kt0 + 1 < KT) {
                const int k = kt0 + 1;
                half8 a = *(const half8*)&p_lds[((k >> 3) * 16 + n) * PSTR +
                                                (k & 7) * 32 + quad * 8];
                oacc = __builtin_amdgcn_mfma_f32_16x16x32_f16(a, cur1, oacc, 0, 0, 0);
            }
        }
        #pragma unroll
        for (int reg = 0; reg < 4; ++reg) {
            const int i = r0 + quad * 4 + reg;
            attn[(((size_t)b * SS + i) * HH + h) * DKK + w * 16 + n] =
                (_Float16)oacc[reg];
        }
    }
}

// ---------------------------------------------------------------------------
extern "C" void kernel_launch(void* const* d_in, const int* in_sizes, int n_in,
                              void* d_out, int out_size, void* d_ws, size_t ws_size,
                              hipStream_t stream) {
    const float* x      = (const float*)d_in[0];
    const float* utT    = (const float*)d_in[1];
    const float* Wk     = (const float*)d_in[2];
    const float* bk     = (const float*)d_in[3];
    const float* Wv     = (const float*)d_in[4];
    const float* bv     = (const float*)d_in[5];
    const float* Wo     = (const float*)d_in[6];
    const float* bo     = (const float*)d_in[7];
    const float* gammas = (const float*)d_in[8];
    float* out = (float*)d_out;

    const size_t per = (size_t)NB * SS * DD;   // 4,194,304 fp16 elems each

    _Float16* p      = (_Float16*)d_ws;
    _Float16* q_ws   = p;  p += per;
    _Float16* vt_ws  = p;  p += per;
    _Float16* attn_h = p;  p += per;           // total ~25.2 MB

    dim3 g1(64, 8);    // 128x128 tiles, M=8192, N=1024 (q||v), cvt fused
    gemm_qv<<<g1, dim3(256), 0, stream>>>(x, Wk, bk, Wv, bv, q_ws, vt_ws);

    dim3 g2(SS / 16, NB * HH);
    attn_mfma<<<g2, dim3(1024), 0, stream>>>(q_ws, vt_ws, utT, gammas, attn_h);

    dim3 g3(64, 4);    // 128x128 tiles, M=8192, N=512, cvt fused
    gemm_out<<<g3, dim3(256), 0, stream>>>(attn_h, Wo, bo, out);
}

// Round 15
// 271.375 us; speedup vs baseline: 1.0322x; 1.0322x over previous
//
#include <hip/hip_runtime.h>
#include <math.h>

#define NB   8
#define SS   1024
#define DD   512
#define HH   8
#define DKK  64
#define NEGF (-3.0e38f)
// score scale folded with log2(e): exp(x) == exp2(x*log2e)
#define SC   (0.125f * 1.4426950408889634f)

// OCCUPANCY LEDGER (R0-R13): residency driver is reported VGPR_Count.
// <=32 -> 2 blk/CU; 36-40 -> 1 blk/CU (~1.25x cost). LDS up to 68.6KB has
// NO residency effect at low VGPR (R10). attn best = R10 body (157.5us).
// GEMM K-loop structure is off the critical path (R11 BK=64 null; R12
// 2-phase null); cvt fusion via fp32 reg-staging REGRESSES +7us (R13,
// m151: reg-staging < GLDS16). R14/R15 = session-best R10 config.
// (R14 bench was an infra failure — container, not kernel.)
#define QSTR 88             // halves; q tile stride
#define SCHUNK (16 * 256)   // floats per score chunk buffer (XOR swizzled)
#define PSTR 280            // halves; attn p rows (phase 3, aliased)

typedef _Float16 half8 __attribute__((ext_vector_type(8)));
typedef float    f32x4 __attribute__((ext_vector_type(4)));

// async 16B/lane global->LDS (wave-uniform LDS base + lane*16)
#define GLDS16(g, l) __builtin_amdgcn_global_load_lds( \
    (const __attribute__((address_space(1))) void*)(g), \
    (__attribute__((address_space(3))) void*)(l), 16, 0, 0)

// ---------------------------------------------------------------------------
// DPP helpers: full-rate VALU cross-lane (no ds_bpermute).
// ---------------------------------------------------------------------------
template<int CTRL, int RM, int BM, bool BC>
__device__ __forceinline__ float dpp_f(float x) {
    return __builtin_bit_cast(float,
        __builtin_amdgcn_update_dpp(0, __builtin_bit_cast(int, x),
                                    CTRL, RM, BM, BC));
}

// inclusive 64-lane prefix sum: row_shr 1/2/4/8 then row_bcast:15 (rows 1,3)
// and row_bcast:31 (rows 2,3). old=0 so masked/invalid lanes add 0.
__device__ __forceinline__ float scan64(float x) {
    x += dpp_f<0x111, 0xf, 0xf, true >(x);   // row_shr:1
    x += dpp_f<0x112, 0xf, 0xf, true >(x);   // row_shr:2
    x += dpp_f<0x114, 0xf, 0xf, true >(x);   // row_shr:4
    x += dpp_f<0x118, 0xf, 0xf, true >(x);   // row_shr:8
    x += dpp_f<0x142, 0xa, 0xf, false>(x);   // row_bcast:15 -> rows 1,3
    x += dpp_f<0x143, 0xc, 0xf, false>(x);   // row_bcast:31 -> rows 2,3
    return x;
}

__device__ __forceinline__ float redsum64(float x) {
    x += dpp_f<0xB1,  0xf, 0xf, true>(x);    // quad_perm [1,0,3,2]  (xor 1)
    x += dpp_f<0x4E,  0xf, 0xf, true>(x);    // quad_perm [2,3,0,1]  (xor 2)
    x += dpp_f<0x141, 0xf, 0xf, true>(x);    // row_half_mirror      (xor 4)
    x += dpp_f<0x140, 0xf, 0xf, true>(x);    // row_mirror           (xor 8)
    x += __shfl_xor(x, 16);
    x += __shfl_xor(x, 32);
    return x;
}

__device__ __forceinline__ float bcast63(float x) {
    return __builtin_bit_cast(float,
        __builtin_amdgcn_readlane(__builtin_bit_cast(int, x), 63));
}

// ---------------------------------------------------------------------------
// cvt: x, Wk, Wv, Wo (fp32) -> fp16 buffers. 8 elems/thread.
// ---------------------------------------------------------------------------
__global__ __launch_bounds__(256) void cvt_fp16(
    const float* __restrict__ x,  _Float16* __restrict__ xh,
    const float* __restrict__ wk, _Float16* __restrict__ wkh,
    const float* __restrict__ wv, _Float16* __restrict__ wvh,
    const float* __restrict__ wo, _Float16* __restrict__ woh)
{
    const size_t NX = (size_t)NB * SS * DD;   // 4194304
    const size_t NW = (size_t)DD * DD;        // 262144
    size_t f = ((size_t)blockIdx.x * 256 + threadIdx.x) * 8;
    const float* src; _Float16* dst; size_t off;
    if (f < NX)               { src = x;  dst = xh;  off = f; }
    else if (f < NX + NW)     { src = wk; dst = wkh; off = f - NX; }
    else if (f < NX + 2*NW)   { src = wv; dst = wvh; off = f - NX - 2*NW + NW; }
    else                      { src = wo; dst = woh; off = f - NX - 2*NW; }
    float4 f0 = *(const float4*)&src[off];
    float4 f1 = *(const float4*)&src[off + 4];
    half8 hv = {(_Float16)f0.x,(_Float16)f0.y,(_Float16)f0.z,(_Float16)f0.w,
                (_Float16)f1.x,(_Float16)f1.y,(_Float16)f1.z,(_Float16)f1.w};
    *(half8*)&dst[off] = hv;
}

// ---------------------------------------------------------------------------
// GEMM #1, m97-style: 128x128 tile, BK=32, global_load_lds staging.
// q = xh@Wk^T + bk -> fp16 [b,h,s,dk]; v = xh@Wv^T + bv -> fp16 [b,h,dk,s].
// ---------------------------------------------------------------------------
__global__ __launch_bounds__(256) void gemm_qv(
    const _Float16* __restrict__ xh,
    const _Float16* __restrict__ wkh, const float* __restrict__ bk,
    const _Float16* __restrict__ wvh, const float* __restrict__ bv,
    _Float16* __restrict__ q_ws, _Float16* __restrict__ vt_ws)
{
    __shared__ __align__(16) _Float16 Ah[128 * 32];   // 8192 B, packed
    __shared__ __align__(16) _Float16 Bh[128 * 32];

    const int m0  = blockIdx.x * 128;
    const int n0c = blockIdx.y * 128;
    const bool is_v = (n0c >= DD);
    const _Float16* __restrict__ Wp = is_v ? wvh : wkh;
    const float*    __restrict__ bp = is_v ? bv : bk;
    const int n0 = n0c & (DD - 1);

    const int tid  = threadIdx.x;
    const int w    = tid >> 6;
    const int lane = tid & 63;
    const int quad = lane >> 4;
    const int n    = lane & 15;
    const int wm   = w >> 1, wn = w & 1;

    // DMA chunk coords: ci = (w*2+c)*64 + lane; row = ci>>2; col8 = (ci&3)*8
    const int ci0 = (w * 2 + 0) * 64 + lane;
    const int ci1 = (w * 2 + 1) * 64 + lane;
    const int r0c = ci0 >> 2, c0c = (ci0 & 3) * 8;
    const int r1c = ci1 >> 2, c1c = (ci1 & 3) * 8;
    _Float16* ldsA0 = &Ah[(w * 2 + 0) * 512];
    _Float16* ldsA1 = &Ah[(w * 2 + 1) * 512];
    _Float16* ldsB0 = &Bh[(w * 2 + 0) * 512];
    _Float16* ldsB1 = &Bh[(w * 2 + 1) * 512];

    f32x4 acc[4][4] = {};

    for (int k0 = 0; k0 < DD; k0 += 32) {
        __syncthreads();   // prior frag reads done
        GLDS16(&xh[(size_t)(m0 + r0c) * DD + k0 + c0c], ldsA0);
        GLDS16(&xh[(size_t)(m0 + r1c) * DD + k0 + c1c], ldsA1);
        GLDS16(&Wp[(size_t)(n0 + r0c) * DD + k0 + c0c], ldsB0);
        GLDS16(&Wp[(size_t)(n0 + r1c) * DD + k0 + c1c], ldsB1);
        __syncthreads();   // compiler drains vmcnt before barrier
        half8 af[4], bf[4];
        #pragma unroll
        for (int mi = 0; mi < 4; ++mi)
            af[mi] = *(const half8*)&Ah[(wm*64 + mi*16 + n) * 32 + quad*8];
        #pragma unroll
        for (int ni = 0; ni < 4; ++ni)
            bf[ni] = *(const half8*)&Bh[(wn*64 + ni*16 + n) * 32 + quad*8];
        #pragma unroll
        for (int mi = 0; mi < 4; ++mi)
            #pragma unroll
            for (int ni = 0; ni < 4; ++ni)
                acc[mi][ni] = __builtin_amdgcn_mfma_f32_16x16x32_f16(
                    af[mi], bf[ni], acc[mi][ni], 0, 0, 0);
    }

    #pragma unroll
    for (int mi = 0; mi < 4; ++mi) {
        #pragma unroll
        for (int ni = 0; ni < 4; ++ni) {
            const int col = n0 + wn*64 + ni*16 + n;   // 0..511
            const int h   = col >> 6;
            const int dk  = col & 63;
            const float bias = bp[col];
            const int gbase = m0 + wm*64 + mi*16 + quad*4;
            const int bidx  = gbase >> 10;
            const int sr    = gbase & (SS - 1);
            if (!is_v) {
                #pragma unroll
                for (int reg = 0; reg < 4; ++reg)
                    q_ws[((size_t)(bidx * HH + h) * SS + sr + reg) * DKK + dk] =
                        (_Float16)(acc[mi][ni][reg] + bias);
            } else {
                _Float16 h4[4];
                #pragma unroll
                for (int reg = 0; reg < 4; ++reg)
                    h4[reg] = (_Float16)(acc[mi][ni][reg] + bias);
                *(uint2*)&vt_ws[((size_t)(bidx * HH + h) * DKK + dk) * SS + sr] =
                    *(uint2*)h4;
            }
        }
    }
}

// ---------------------------------------------------------------------------
// GEMM #2, m97-style: out = attn_h @ Wo^T + bo (A fp16 from attn, out fp32)
// ---------------------------------------------------------------------------
__global__ __launch_bounds__(256) void gemm_out(
    const _Float16* __restrict__ A,
    const _Float16* __restrict__ woh, const float* __restrict__ bo,
    float* __restrict__ out)
{
    __shared__ __align__(16) _Float16 Ah[128 * 32];
    __shared__ __align__(16) _Float16 Bh[128 * 32];

    const int m0 = blockIdx.x * 128;
    const int n0 = blockIdx.y * 128;

    const int tid  = threadIdx.x;
    const int w    = tid >> 6;
    const int lane = tid & 63;
    const int quad = lane >> 4;
    const int n    = lane & 15;
    const int wm   = w >> 1, wn = w & 1;

    const int ci0 = (w * 2 + 0) * 64 + lane;
    const int ci1 = (w * 2 + 1) * 64 + lane;
    const int r0c = ci0 >> 2, c0c = (ci0 & 3) * 8;
    const int r1c = ci1 >> 2, c1c = (ci1 & 3) * 8;
    _Float16* ldsA0 = &Ah[(w * 2 + 0) * 512];
    _Float16* ldsA1 = &Ah[(w * 2 + 1) * 512];
    _Float16* ldsB0 = &Bh[(w * 2 + 0) * 512];
    _Float16* ldsB1 = &Bh[(w * 2 + 1) * 512];

    f32x4 acc[4][4] = {};

    for (int k0 = 0; k0 < DD; k0 += 32) {
        __syncthreads();
        GLDS16(&A[(size_t)(m0 + r0c) * DD + k0 + c0c], ldsA0);
        GLDS16(&A[(size_t)(m0 + r1c) * DD + k0 + c1c], ldsA1);
        GLDS16(&woh[(size_t)(n0 + r0c) * DD + k0 + c0c], ldsB0);
        GLDS16(&woh[(size_t)(n0 + r1c) * DD + k0 + c1c], ldsB1);
        __syncthreads();
        half8 af[4], bf[4];
        #pragma unroll
        for (int mi = 0; mi < 4; ++mi)
            af[mi] = *(const half8*)&Ah[(wm*64 + mi*16 + n) * 32 + quad*8];
        #pragma unroll
        for (int ni = 0; ni < 4; ++ni)
            bf[ni] = *(const half8*)&Bh[(wn*64 + ni*16 + n) * 32 + quad*8];
        #pragma unroll
        for (int mi = 0; mi < 4; ++mi)
            #pragma unroll
            for (int ni = 0; ni < 4; ++ni)
                acc[mi][ni] = __builtin_amdgcn_mfma_f32_16x16x32_f16(
                    af[mi], bf[ni], acc[mi][ni], 0, 0, 0);
    }

    #pragma unroll
    for (int mi = 0; mi < 4; ++mi) {
        #pragma unroll
        for (int ni = 0; ni < 4; ++ni) {
            const int col  = n0 + wn*64 + ni*16 + n;
            const float bias = bo[col];
            const int gbase = m0 + wm*64 + mi*16 + quad*4;
            #pragma unroll
            for (int reg = 0; reg < 4; ++reg)
                out[(size_t)(gbase + reg) * DD + col] = acc[mi][ni][reg] + bias;
        }
    }
}

// ---------------------------------------------------------------------------
// MFMA attention — R10 body (session best: 157.5us, VGPR 28, 2 blk/CU):
// single-barrier Phase 1 (#pragma unroll 1 dynamic loop, per-chunk buffers),
// swapped-operand QK^T, XOR swizzle, R9 Phase 2 (no cs[16]), flat PV.
// Known-toxic (do not retry): forced 2-blk/CU launch_bounds (R3, spill);
// reported VGPR > 32 (R5-R8); sched_barrier-pinned raw barriers + manual
// cross-barrier prefetch (R5, m141); 16-wave PV + o_red; utT fold + tmax;
// 8-wave blocks (old session); fp32 reg-staged cvt fusion (R13, +7us).
// ---------------------------------------------------------------------------
__global__ __launch_bounds__(1024) void attn_mfma(
    const _Float16* __restrict__ q,   // [B,H,S,DK] fp16 (K = Q)
    const _Float16* __restrict__ vt,  // [B,H,DK,S] fp16 (V transposed)
    const float* __restrict__ utT,    // [B,S,S]
    const float* __restrict__ gammas, // [H]
    _Float16* __restrict__ attn)      // [B,S,H,DK] fp16
{
    // phase 1: 4 x SCHUNK f32 = 65536 B; phase 3 aliases 4x16xPSTR halves
    // (35840 B) inside it. + q_lds 2816 B = 68352 B total.
    __shared__ __align__(16) unsigned char smem[4 * SCHUNK * 4];
    __shared__ __align__(16) _Float16 q_lds[16 * QSTR];
    float*    s_lds = (float*)smem;
    _Float16* p_lds = (_Float16*)smem;

    const int tid  = threadIdx.x;
    const int w    = tid >> 6;
    const int lane = tid & 63;
    const int quad = lane >> 4;
    const int n    = lane & 15;
    const int bh   = blockIdx.y;
    const int b    = bh >> 3;
    const int h    = bh & 7;
    // heavy-first (LPT): largest r0 dispatched first, light blocks fill tail
    const int r0   = ((SS / 16 - 1) - blockIdx.x) * 16;

    const _Float16* __restrict__ kq  = q  + (size_t)bh * SS * DKK;
    const _Float16* __restrict__ vtp = vt + (size_t)bh * DKK * SS;

    const int nchunk = (r0 + 16 + 255) >> 8;   // 1..4, block-uniform
    const int nt     = nchunk * 4;
    const int i_lane = r0 + n;   // q-row owned by this lane in phase 1

    // stage Q tile into LDS (keeps qa fragments out of long-lived VGPRs)
    if (tid < 256) {
        const int row = tid >> 4;
        const int c   = tid & 15;
        *(uint2*)&q_lds[row * QSTR + c * 4] =
            *(const uint2*)&kq[(size_t)(r0 + row) * DKK + c * 4];
    }
    __syncthreads();

    const float* __restrict__ utrow = &utT[((size_t)b * SS + i_lane) * SS];
    const int scol = (w * 16 + quad * 4) ^ ((n & 7) << 2);   // store swizzle
    const int pcol = lane ^ ((w & 7) << 2);                  // pull swizzle

    // ---- Phase 1: dynamic loop, per-chunk buffers, NO inter-chunk barrier
    #pragma unroll 1
    for (int c0 = 0; c0 < nchunk; ++c0) {
        const int jbase = c0 * 256 + w * 16;
        f32x4 v;
        if (jbase <= r0 + 15) {        // wave-uniform guard
            half8 qa0 = *(const half8*)&q_lds[n * QSTR + quad * 8];
            half8 qa1 = *(const half8*)&q_lds[n * QSTR + 32 + quad * 8];
            const _Float16* krow = &kq[(size_t)(jbase + n) * DKK];
            half8 k0 = *(const half8*)&krow[quad * 8];
            half8 k1 = *(const half8*)&krow[32 + quad * 8];
            f32x4 ut = *(const f32x4*)&utrow[jbase + quad * 4];
            f32x4 d = {0.f, 0.f, 0.f, 0.f};
            d = __builtin_amdgcn_mfma_f32_16x16x32_f16(k0, qa0, d, 0, 0, 0);
            d = __builtin_amdgcn_mfma_f32_16x16x32_f16(k1, qa1, d, 0, 0, 0);
            #pragma unroll
            for (int reg = 0; reg < 4; ++reg) {
                const int j = jbase + quad * 4 + reg;
                v[reg] = (j <= i_lane) ? d[reg] * SC * ut[reg] : NEGF;
            }
        } else {
            v = (f32x4){NEGF, NEGF, NEGF, NEGF};
        }
        *(f32x4*)&s_lds[c0 * SCHUNK + n * 256 + scol] = v;
    }
    __syncthreads();   // ONE barrier for the whole phase

    float sreg[16];
    #pragma unroll
    for (int c0 = 0; c0 < 4; ++c0) {
        if (c0 < nchunk) {
            #pragma unroll
            for (int ttl = 0; ttl < 4; ++ttl)
                sreg[c0 * 4 + ttl] =
                    s_lds[c0 * SCHUNK + w * 256 + ttl * 64 + pcol];
        }
    }

    // ---- Phase 2 ----
    const int i_row = r0 + w;
    const int ntw_u = (i_row >> 6) + 1;          // tiles intersecting causal
    const int ntw   = (nt < ntw_u) ? nt : ntw_u; // wave-uniform

    // pass A: z1 = row total of e — plain sum per lane + one butterfly.
    float z1acc = 0.f;
    #pragma unroll
    for (int t2 = 0; t2 < 16; ++t2)
        if (t2 < ntw) z1acc += __builtin_amdgcn_exp2f(sreg[t2]);
    const float z1     = redsum64(z1acc);
    const float inv_z1 = 1.0f / z1;

    const float g     = gammas[h];
    const float gl2   = -log1pf(__expf(g)) * 1.4426950408889634f; // gamma*log2e
    const float flane = (float)lane;

    // pass B: inline scan (e recomputed bit-identically), decay, numerator
    float carry = 0.f;
    float z2 = 0.f;
    #pragma unroll
    for (int t2 = 0; t2 < 16; ++t2) {
        if (t2 < ntw) {
            const float e  = __builtin_amdgcn_exp2f(sreg[t2]); // masked -> 0
            const float xv = scan64(e);
            const float cs = carry + xv;
            carry += bcast63(xv);
            const float pe = (float)(i_row - t2 * 64) - flane;  // <0 only masked
            const float dd = fmaxf((z1 - cs) * pe, 0.0f) * inv_z1;
            float te = __builtin_amdgcn_exp2f(__builtin_amdgcn_sqrtf(dd) * gl2);
            te = fmaxf(te, 1e-5f);            // gamma<0 -> te<=1, no hi clamp
            const float p = __builtin_amdgcn_exp2f(sreg[t2] * te); // masked -> 0
            sreg[t2] = p;
            z2 += p;
        } else {
            sreg[t2] = 0.f;                   // tiles beyond causal extent
        }
    }
    z2 = redsum64(z2);
    const float inv_z2 = 1.0f / z2;

    __syncthreads();   // all phase-1 s_lds pulls complete before p writes

    // ---- Phase 3: flat PV, 2-deep prefetch ----
    #pragma unroll
    for (int c0 = 0; c0 < 4; ++c0) {
        if (c0 < nchunk) {
            #pragma unroll
            for (int ttl = 0; ttl < 4; ++ttl)
                p_lds[c0 * 16 * PSTR + w * PSTR + ttl * 64 + lane] =
                    (_Float16)(sreg[c0 * 4 + ttl] * inv_z2);
        }
    }

    const int KT = (r0 + 16 + 31) >> 5;   // 1..32 k-tiles of 32 cols, uniform
    const _Float16* vrow = &vtp[(size_t)(w * 16 + n) * SS];
    half8 vb[2] = {};
    if (w < 4) {
        #pragma unroll
        for (int u = 0; u < 2; ++u)
            if (u < KT) vb[u] = *(const half8*)&vrow[u * 32 + quad * 8];
    }
    __syncthreads();

    f32x4 oacc = {0.f, 0.f, 0.f, 0.f};
    if (w < 4) {
        for (int kt0 = 0; kt0 < KT; kt0 += 2) {
            half8 cur0 = vb[0], cur1 = vb[1];
            if (kt0 + 2 < KT) vb[0] = *(const half8*)&vrow[(kt0 + 2) * 32 + quad * 8];
            if (kt0 + 3 < KT) vb[1] = *(const half8*)&vrow[(kt0 + 3) * 32 + quad * 8];
            {
                half8 a = *(const half8*)&p_lds[((kt0 >> 3) * 16 + n) * PSTR +
                                                (kt0 & 7) * 32 + quad * 8];
                oacc = __builtin_amdgcn_mfma_f32_16x16x32_f16(a, cur0, oacc, 0, 0, 0);
            }
            if (kt0 + 1 < KT) {
                const int k = kt0 + 1;
                half8 a = *(const half8*)&p_lds[((k >> 3) * 16 + n) * PSTR +
                                                (k & 7) * 32 + quad * 8];
                oacc = __builtin_amdgcn_mfma_f32_16x16x32_f16(a, cur1, oacc, 0, 0, 0);
            }
        }
        #pragma unroll
        for (int reg = 0; reg < 4; ++reg) {
            const int i = r0 + quad * 4 + reg;
            attn[(((size_t)b * SS + i) * HH + h) * DKK + w * 16 + n] =
                (_Float16)oacc[reg];
        }
    }
}

// ---------------------------------------------------------------------------
extern "C" void kernel_launch(void* const* d_in, const int* in_sizes, int n_in,
                              void* d_out, int out_size, void* d_ws, size_t ws_size,
                              hipStream_t stream) {
    const float* x      = (const float*)d_in[0];
    const float* utT    = (const float*)d_in[1];
    const float* Wk     = (const float*)d_in[2];
    const float* bk     = (const float*)d_in[3];
    const float* Wv     = (const float*)d_in[4];
    const float* bv     = (const float*)d_in[5];
    const float* Wo     = (const float*)d_in[6];
    const float* bo     = (const float*)d_in[7];
    const float* gammas = (const float*)d_in[8];
    float* out = (float*)d_out;

    const size_t NX  = (size_t)NB * SS * DD;   // 4,194,304
    const size_t NW  = (size_t)DD * DD;        // 262,144
    const size_t per = NX;

    _Float16* p      = (_Float16*)d_ws;
    _Float16* xh     = p;  p += NX;
    _Float16* wkh    = p;  p += NW;
    _Float16* wvh    = p;  p += NW;
    _Float16* woh    = p;  p += NW;
    _Float16* q_ws   = p;  p += per;
    _Float16* vt_ws  = p;  p += per;
    _Float16* attn_h = p;  p += per;           // total ~33.5 MB

    const int cvt_blocks = (int)((NX + 3 * NW) / 8 / 256);  // 2432
    cvt_fp16<<<cvt_blocks, dim3(256), 0, stream>>>(
        x, xh, Wk, wkh, Wv, wvh, Wo, woh);

    dim3 g1(64, 8);    // 128x128 tiles, M=8192, N=1024 (q||v)
    gemm_qv<<<g1, dim3(256), 0, stream>>>(xh, wkh, bk, wvh, bv, q_ws, vt_ws);

    dim3 g2(SS / 16, NB * HH);
    attn_mfma<<<g2, dim3(1024), 0, stream>>>(q_ws, vt_ws, utT, gammas, attn_h);

    dim3 g3(64, 4);    // 128x128 tiles, M=8192, N=512
    gemm_out<<<g3, dim3(256), 0, stream>>>(attn_h, woh, bo, out);
}